// Round 1
// baseline (37.095 us; speedup 1.0000x reference)
//
#include <hip/hip_runtime.h>
#include <stdint.h>

// QuantizedBn2d requantization:
//   subsum = xq*w - xq*z2 - w*z1 + z1*z2 + bias            (per (b,c) params)
//   mult   = gemmlowp doubling-high-mul(subsum << sneg, M0)
//   out    = clamp(round_rshift(mult, spos) + z3, -128, 127)
//
// Memory-bound: 205 MB total traffic -> ~33us floor @ 6.3 TB/s.

__device__ __forceinline__ float qbn_elem(float xv, int A, int D, long long m0,
                                          int spos, int mask, int halfmask, int z3v) {
    int xq = __float2int_rn(xv);
    int sub = xq * A + D;                      // == (subsum << sneg), fits int32
    // multiply_M: saturating rounding doubling high mul (overflow branch dead: m0 > 0)
    long long p = (long long)sub * m0;
    p += (p >= 0) ? (1LL << 30) : (1LL - (1LL << 30));
    int mult = (int)((p < 0) ? -((-p) >> 31) : (p >> 31));
    // shifting4d: rounding right shift by spos (spos==0 -> identity)
    int rem = mult & mask;
    int thr = halfmask + (mult < 0 ? 1 : 0);
    int tot = (mult >> spos) + ((rem > thr) ? 1 : 0) + z3v;
    tot = min(127, max(-128, tot));
    return (float)tot;
}

__global__ __launch_bounds__(256) void QuantizedBn2d_kernel(
    const float* __restrict__ x,
    const int* __restrict__ bc,
    const int* __restrict__ weight,
    const int* __restrict__ bias,
    const int* __restrict__ z1,
    const int* __restrict__ z2,
    const int* __restrict__ z3,
    const int* __restrict__ M0,
    const int* __restrict__ shift,
    float* __restrict__ out,
    int C, int HW)
{
    const int blk = blockIdx.x;            // = b*C + c
    const int b = blk / C;
    const int c = blk - b * C;
    const int k = bc[b];

    const int wv  = weight[k * C + c];
    const int bsv = bias[k * C + c];
    const int z1v = z1[k];
    const int z2v = z2[k];
    const int z3v = z3[k];
    const long long m0 = (long long)M0[k];
    const int s = shift[k];
    const int sneg = (s < 0) ? -s : 0;     // pre-left-shift amount
    const int spos = (s > 0) ?  s : 0;     // rounding right-shift amount

    // subsum << sneg == xq * A + D  with:
    const int A = (wv - z2v) << sneg;
    const int D = (z1v * z2v - wv * z1v + bsv) << sneg;
    const int mask = (1 << spos) - 1;
    const int halfmask = mask >> 1;

    const size_t base = (size_t)blk * (size_t)HW;
    const float4* __restrict__ xin  = (const float4*)(x + base);
    float4* __restrict__ outp = (float4*)(out + base);

    const int nv = HW >> 2;
    for (int i = threadIdx.x; i < nv; i += blockDim.x) {
        float4 v = xin[i];
        float4 r;
        r.x = qbn_elem(v.x, A, D, m0, spos, mask, halfmask, z3v);
        r.y = qbn_elem(v.y, A, D, m0, spos, mask, halfmask, z3v);
        r.z = qbn_elem(v.z, A, D, m0, spos, mask, halfmask, z3v);
        r.w = qbn_elem(v.w, A, D, m0, spos, mask, halfmask, z3v);
        outp[i] = r;
    }
    // tail (HW not divisible by 4) — HW=3136 here so normally empty
    for (int i = (nv << 2) + threadIdx.x; i < HW; i += blockDim.x) {
        out[base + i] = qbn_elem(x[base + i], A, D, m0, spos, mask, halfmask, z3v);
    }
}

extern "C" void kernel_launch(void* const* d_in, const int* in_sizes, int n_in,
                              void* d_out, int out_size, void* d_ws, size_t ws_size,
                              hipStream_t stream) {
    const float* x      = (const float*)d_in[0];
    const int*   bc     = (const int*)d_in[1];
    const int*   weight = (const int*)d_in[2];
    const int*   bias   = (const int*)d_in[3];
    const int*   z1     = (const int*)d_in[4];
    const int*   z2     = (const int*)d_in[5];
    const int*   z3     = (const int*)d_in[6];
    const int*   M0     = (const int*)d_in[7];
    const int*   shift  = (const int*)d_in[8];
    float* out = (float*)d_out;

    const int B  = in_sizes[1];             // 64
    const int K  = in_sizes[4];             // 8
    const int C  = in_sizes[2] / K;         // 128
    const int HW = in_sizes[0] / (B * C);   // 3136

    const int nblocks = B * C;              // 8192
    QuantizedBn2d_kernel<<<nblocks, 256, 0, stream>>>(
        x, bc, weight, bias, z1, z2, z3, M0, shift, out, C, HW);
}

// Round 2
// 36.858 us; speedup vs baseline: 1.0064x; 1.0064x over previous
//
#include <hip/hip_runtime.h>
#include <stdint.h>

// QuantizedBn2d requantization:
//   subsum = xq*w - xq*z2 - w*z1 + z1*z2 + bias            (per (b,c) params)
//   mult   = gemmlowp doubling-high-mul(subsum << sneg, M0)
//   out    = clamp(round_rshift(mult, spos) + z3, -128, 127)
//
// Memory-bound. Within a dispatch there is zero data reuse, but x (103 MB)
// fits in the 256 MiB L3 across graph replays. Non-temporal stores keep the
// 100 MB output stream from evicting x -> reads come from L3, HBM carries
// only the write stream.

typedef float f4_t __attribute__((ext_vector_type(4)));

__device__ __forceinline__ float qbn_elem(float xv, int A, int D, long long m0,
                                          int spos, int mask, int halfmask, int z3v) {
    int xq = __float2int_rn(xv);
    int sub = xq * A + D;                      // == (subsum << sneg), fits int32
    // multiply_M: saturating rounding doubling high mul (overflow branch dead: m0 > 0)
    long long p = (long long)sub * m0;
    p += (p >= 0) ? (1LL << 30) : (1LL - (1LL << 30));
    int mult = (int)((p < 0) ? -((-p) >> 31) : (p >> 31));
    // shifting4d: rounding right shift by spos (spos==0 -> identity)
    int rem = mult & mask;
    int thr = halfmask + (mult < 0 ? 1 : 0);
    int tot = (mult >> spos) + ((rem > thr) ? 1 : 0) + z3v;
    tot = min(127, max(-128, tot));
    return (float)tot;
}

__global__ __launch_bounds__(256) void QuantizedBn2d_kernel(
    const float* __restrict__ x,
    const int* __restrict__ bc,
    const int* __restrict__ weight,
    const int* __restrict__ bias,
    const int* __restrict__ z1,
    const int* __restrict__ z2,
    const int* __restrict__ z3,
    const int* __restrict__ M0,
    const int* __restrict__ shift,
    float* __restrict__ out,
    int C, int HW)
{
    const int blk = blockIdx.x;            // = b*C + c
    const int b = blk / C;
    const int c = blk - b * C;
    const int k = bc[b];

    const int wv  = weight[k * C + c];
    const int bsv = bias[k * C + c];
    const int z1v = z1[k];
    const int z2v = z2[k];
    const int z3v = z3[k];
    const long long m0 = (long long)M0[k];
    const int s = shift[k];
    const int sneg = (s < 0) ? -s : 0;     // pre-left-shift amount
    const int spos = (s > 0) ?  s : 0;     // rounding right-shift amount

    // subsum << sneg == xq * A + D  with:
    const int A = (wv - z2v) << sneg;
    const int D = (z1v * z2v - wv * z1v + bsv) << sneg;
    const int mask = (1 << spos) - 1;
    const int halfmask = mask >> 1;

    const size_t base = (size_t)blk * (size_t)HW;
    const f4_t* __restrict__ xin = (const f4_t*)(x + base);
    f4_t* __restrict__ outp = (f4_t*)(out + base);

    const int nv = HW >> 2;
    for (int i = threadIdx.x; i < nv; i += blockDim.x) {
        f4_t v = xin[i];                    // cached load: keep x L3-resident
        f4_t r;
        r.x = qbn_elem(v.x, A, D, m0, spos, mask, halfmask, z3v);
        r.y = qbn_elem(v.y, A, D, m0, spos, mask, halfmask, z3v);
        r.z = qbn_elem(v.z, A, D, m0, spos, mask, halfmask, z3v);
        r.w = qbn_elem(v.w, A, D, m0, spos, mask, halfmask, z3v);
        __builtin_nontemporal_store(r, &outp[i]);   // stream write past L2/L3
    }
    // tail (HW not divisible by 4) — HW=3136 here so normally empty
    for (int i = (nv << 2) + threadIdx.x; i < HW; i += blockDim.x) {
        float r = qbn_elem(x[base + i], A, D, m0, spos, mask, halfmask, z3v);
        __builtin_nontemporal_store(r, &out[base + i]);
    }
}

extern "C" void kernel_launch(void* const* d_in, const int* in_sizes, int n_in,
                              void* d_out, int out_size, void* d_ws, size_t ws_size,
                              hipStream_t stream) {
    const float* x      = (const float*)d_in[0];
    const int*   bc     = (const int*)d_in[1];
    const int*   weight = (const int*)d_in[2];
    const int*   bias   = (const int*)d_in[3];
    const int*   z1     = (const int*)d_in[4];
    const int*   z2     = (const int*)d_in[5];
    const int*   z3     = (const int*)d_in[6];
    const int*   M0     = (const int*)d_in[7];
    const int*   shift  = (const int*)d_in[8];
    float* out = (float*)d_out;

    const int B  = in_sizes[1];             // 64
    const int K  = in_sizes[4];             // 8
    const int C  = in_sizes[2] / K;         // 128
    const int HW = in_sizes[0] / (B * C);   // 3136

    const int nblocks = B * C;              // 8192
    QuantizedBn2d_kernel<<<nblocks, 256, 0, stream>>>(
        x, bc, weight, bias, z1, z2, z3, M0, shift, out, C, HW);
}

// Round 3
// 36.481 us; speedup vs baseline: 1.0168x; 1.0103x over previous
//
#include <hip/hip_runtime.h>
#include <stdint.h>

// QuantizedBn2d requantization:
//   subsum = xq*w - xq*z2 - w*z1 + z1*z2 + bias            (per (b,c) params)
//   mult   = gemmlowp doubling-high-mul(subsum << sneg, M0)
//   out    = clamp(round_rshift(mult, spos) + z3, -128, 127)
//
// Memory-bound at the read+write copy ceiling (~6.3 TB/s). This version
// maximizes per-wave MLP: the common shape (HW=3136 -> 784 float4 / block,
// 256 threads) is fully unrolled -- 3 unconditional loads + 16-lane tail
// issued before any compute, then compute, then nt stores. No loop carried
// branches.

typedef float f4_t __attribute__((ext_vector_type(4)));

__device__ __forceinline__ float qbn_elem(float xv, int A, int D, long long m0,
                                          int spos, int mask, int halfmask, int z3v) {
    int xq = __float2int_rn(xv);
    int sub = xq * A + D;                      // == (subsum << sneg), fits int32
    // multiply_M: saturating rounding doubling high mul (overflow branch dead: m0 > 0)
    long long p = (long long)sub * m0;
    p += (p >= 0) ? (1LL << 30) : (1LL - (1LL << 30));
    int mult = (int)((p < 0) ? -((-p) >> 31) : (p >> 31));
    // shifting4d: rounding right shift by spos (spos==0 -> identity)
    int rem = mult & mask;
    int thr = halfmask + (mult < 0 ? 1 : 0);
    int tot = (mult >> spos) + ((rem > thr) ? 1 : 0) + z3v;
    tot = min(127, max(-128, tot));
    return (float)tot;
}

__device__ __forceinline__ f4_t qbn_vec(f4_t v, int A, int D, long long m0,
                                        int spos, int mask, int halfmask, int z3v) {
    f4_t r;
    r.x = qbn_elem(v.x, A, D, m0, spos, mask, halfmask, z3v);
    r.y = qbn_elem(v.y, A, D, m0, spos, mask, halfmask, z3v);
    r.z = qbn_elem(v.z, A, D, m0, spos, mask, halfmask, z3v);
    r.w = qbn_elem(v.w, A, D, m0, spos, mask, halfmask, z3v);
    return r;
}

__global__ __launch_bounds__(256) void QuantizedBn2d_kernel(
    const float* __restrict__ x,
    const int* __restrict__ bc,
    const int* __restrict__ weight,
    const int* __restrict__ bias,
    const int* __restrict__ z1,
    const int* __restrict__ z2,
    const int* __restrict__ z3,
    const int* __restrict__ M0,
    const int* __restrict__ shift,
    float* __restrict__ out,
    int C, int HW)
{
    const int blk = blockIdx.x;            // = b*C + c
    const int b = blk / C;
    const int c = blk - b * C;
    const int k = bc[b];

    const int wv  = weight[k * C + c];
    const int bsv = bias[k * C + c];
    const int z1v = z1[k];
    const int z2v = z2[k];
    const int z3v = z3[k];
    const long long m0 = (long long)M0[k];
    const int s = shift[k];
    const int sneg = (s < 0) ? -s : 0;     // pre-left-shift amount
    const int spos = (s > 0) ?  s : 0;     // rounding right-shift amount

    // subsum << sneg == xq * A + D  with:
    const int A = (wv - z2v) << sneg;
    const int D = (z1v * z2v - wv * z1v + bsv) << sneg;
    const int mask = (1 << spos) - 1;
    const int halfmask = mask >> 1;

    const size_t base = (size_t)blk * (size_t)HW;
    const f4_t* __restrict__ xin = (const f4_t*)(x + base);
    f4_t* __restrict__ outp = (f4_t*)(out + base);

    const int nv  = HW >> 2;
    const int tid = threadIdx.x;

    if (nv == 3 * 256 + 16) {
        // Specialized path for HW=3136: issue all independent loads first.
        const bool tail = tid < 16;
        f4_t v0 = xin[tid];
        f4_t v1 = xin[tid + 256];
        f4_t v2 = xin[tid + 512];
        f4_t v3;
        if (tail) v3 = xin[768 + tid];

        f4_t r0 = qbn_vec(v0, A, D, m0, spos, mask, halfmask, z3v);
        f4_t r1 = qbn_vec(v1, A, D, m0, spos, mask, halfmask, z3v);
        f4_t r2 = qbn_vec(v2, A, D, m0, spos, mask, halfmask, z3v);

        __builtin_nontemporal_store(r0, &outp[tid]);
        __builtin_nontemporal_store(r1, &outp[tid + 256]);
        __builtin_nontemporal_store(r2, &outp[tid + 512]);
        if (tail) {
            f4_t r3 = qbn_vec(v3, A, D, m0, spos, mask, halfmask, z3v);
            __builtin_nontemporal_store(r3, &outp[768 + tid]);
        }
        return;
    }

    // Generic fallback.
    for (int i = tid; i < nv; i += blockDim.x) {
        f4_t v = xin[i];
        f4_t r = qbn_vec(v, A, D, m0, spos, mask, halfmask, z3v);
        __builtin_nontemporal_store(r, &outp[i]);
    }
    for (int i = (nv << 2) + tid; i < HW; i += blockDim.x) {
        float r = qbn_elem(x[base + i], A, D, m0, spos, mask, halfmask, z3v);
        __builtin_nontemporal_store(r, &out[base + i]);
    }
}

extern "C" void kernel_launch(void* const* d_in, const int* in_sizes, int n_in,
                              void* d_out, int out_size, void* d_ws, size_t ws_size,
                              hipStream_t stream) {
    const float* x      = (const float*)d_in[0];
    const int*   bc     = (const int*)d_in[1];
    const int*   weight = (const int*)d_in[2];
    const int*   bias   = (const int*)d_in[3];
    const int*   z1     = (const int*)d_in[4];
    const int*   z2     = (const int*)d_in[5];
    const int*   z3     = (const int*)d_in[6];
    const int*   M0     = (const int*)d_in[7];
    const int*   shift  = (const int*)d_in[8];
    float* out = (float*)d_out;

    const int B  = in_sizes[1];             // 64
    const int K  = in_sizes[4];             // 8
    const int C  = in_sizes[2] / K;         // 128
    const int HW = in_sizes[0] / (B * C);   // 3136

    const int nblocks = B * C;              // 8192
    QuantizedBn2d_kernel<<<nblocks, 256, 0, stream>>>(
        x, bc, weight, bias, z1, z2, z3, M0, shift, out, C, HW);
}